// Round 4
// baseline (228.324 us; speedup 1.0000x reference)
//
#include <hip/hip_runtime.h>

#define BATCH 4
#define CIN 1024
#define T 512
#define HW 49
#define C 2048
#define D 128
#define L 101
#define HALF 50
#define OUTD 128

#if defined(__has_builtin)
#if __has_builtin(__builtin_amdgcn_global_load_lds)
#define HAS_GLLDS 1
#endif
#endif

__device__ __forceinline__ void gl2lds16(const float4* g, float4* l) {
#ifdef HAS_GLLDS
    __builtin_amdgcn_global_load_lds(
        (const __attribute__((address_space(1))) void*)g,
        (__attribute__((address_space(3))) void*)l, 16, 0, 0);
#else
    *l = *g;
#endif
}

// ---------------------------------------------------------------------------
// prep: tiled transpose Wp [D][C] -> WpT [C][D]; Wf [OUTD][L] -> WfT [L][OUTD]
// ---------------------------------------------------------------------------
__global__ __launch_bounds__(256) void prep_kernel(const float* __restrict__ Wp,
                                                   const float* __restrict__ Wf,
                                                   float* __restrict__ WpT,
                                                   float* __restrict__ WfT) {
    __shared__ float tile[32][33];
    int bid = blockIdx.x;
    int tid = threadIdx.x;
    if (bid < 256) {
        int ct = bid & 63, dt = bid >> 6;
        int c0 = ct * 32, d0 = dt * 32;
        int col = tid & 31, row = tid >> 5;
#pragma unroll
        for (int i = 0; i < 4; ++i) {
            int dl = row + i * 8;
            tile[dl][col] = Wp[(long long)(d0 + dl) * C + c0 + col];
        }
        __syncthreads();
#pragma unroll
        for (int i = 0; i < 4; ++i) {
            int cc = row + i * 8;
            WpT[(long long)(c0 + cc) * D + d0 + col] = tile[col][cc];
        }
    } else {
        int idx = (bid - 256) * 256 + tid;
        if (idx < L * OUTD) {
            int l = idx >> 7, o = idx & 127;
            WfT[idx] = Wf[o * L + l];
        }
    }
}

// ---------------------------------------------------------------------------
// mean: spatial mean over 49 -> feats[b][c][t].
// 8192 blocks x 4 chunks of 128 rows. Double-buffered LDS staged via
// global_load_lds, counted s_waitcnt vmcnt(7), raw s_barrier — keeps the
// next chunk's loads in flight across the barrier (T3/T4 pattern).
// Per wave per chunk: exactly 7 vmcnt ticks (6 full + 1 eight-lane load).
// ---------------------------------------------------------------------------
__global__ __launch_bounds__(256) void mean_kernel(const float* __restrict__ x1,
                                                   const float* __restrict__ x2,
                                                   float* __restrict__ feats) {
    __shared__ __align__(16) float4 buf[2][1568];        // 2 x 25088 B

    const long long Mrows = (long long)BATCH * CIN * T;  // 2097152 per input
    long long row0 = (long long)blockIdx.x * 512;        // 4 chunks x 128 rows
    const float* src;
    long long m0;
    int half;
    if (row0 < Mrows) { src = x1; m0 = row0; half = 0; }
    else              { src = x2; m0 = row0 - Mrows; half = 1; }

    const float4* src4 = reinterpret_cast<const float4*>(src) + (((long long)m0 * HW) >> 2);
    int tid  = threadIdx.x;
    int w    = tid >> 6;      // wave id 0..3
    int lane = tid & 63;

    // per-chunk float4 span = 128*49/4 = 1568; per wave 392 = 6*64 + 8
    const int wofs = w * 392;

    // reduce-phase ids
    int r = tid >> 1, p = tid & 1;

    auto issue = [&](int ck) {
        const float4* gb = src4 + (long long)ck * 1568 + wofs;
        float4* lb = &buf[ck & 1][wofs];
#pragma unroll
        for (int k = 0; k < 6; ++k)
            gl2lds16(gb + k * 64 + lane, lb + k * 64 + lane);
        if (lane < 8)
            gl2lds16(gb + 384 + lane, lb + 384 + lane);
    };

    issue(0);   // prologue

#pragma unroll
    for (int ck = 0; ck < 4; ++ck) {
        if (ck < 3) {
            issue(ck + 1);
            asm volatile("s_waitcnt vmcnt(7)" ::: "memory");
        } else {
            asm volatile("s_waitcnt vmcnt(0)" ::: "memory");
        }
        __builtin_amdgcn_s_barrier();          // chunk ck data ready (all waves)
        __builtin_amdgcn_sched_barrier(0);     // pin: no LDS reads above

        // reduce: 2 threads per row, 128 rows
        const float* rowp = reinterpret_cast<const float*>(buf[ck & 1]) + r * HW + p * 24;
        float s0 = 0.f, s1 = 0.f, s2 = 0.f, s3 = 0.f;
#pragma unroll
        for (int j = 0; j < 6; ++j) {
            s0 += rowp[j];
            s1 += rowp[6 + j];
            s2 += rowp[12 + j];
            s3 += rowp[18 + j];
        }
        float s = (s0 + s1) + (s2 + s3);
        if (p == 0) s += reinterpret_cast<const float*>(buf[ck & 1])[r * HW + 48];
        s += __shfl_xor(s, 1);
        if (p == 0) {
            long long m = m0 + ck * 128 + r;
            long long b = m >> 19;                 // / (1024*512)
            long long rem = m & ((1LL << 19) - 1); // c*512 + t
            feats[(b << 20) + ((long long)half << 19) + rem] = s * (1.0f / 49.0f);
        }
        __builtin_amdgcn_s_barrier();          // safe to overwrite buf[ck&1]
    }
}

// ---------------------------------------------------------------------------
// proj: x[b,t,d] = sum_c feats[b,c,t] * WpT[c,d], split-K.
// grid = 4(b) * 32(t-tile of 16) * 8(kc of 256 c) = 1024 blocks, 256 thr.
// ---------------------------------------------------------------------------
__global__ __launch_bounds__(256) void proj_kernel(const float* __restrict__ feats,
                                                   const float* __restrict__ WpT,
                                                   float* __restrict__ part) {
    int bid = blockIdx.x;
    int kc = bid & 7;
    int tt = (bid >> 3) & 31;
    int b  = bid >> 8;
    int c0 = kc * 256;
    int t0 = tt * 16;

    __shared__ __align__(16) float fl[256 * 16];   // 16 KB
    float4* fl4 = reinterpret_cast<float4*>(fl);
    const float4* feats4 = reinterpret_cast<const float4*>(feats);
    int tid = threadIdx.x;
#pragma unroll
    for (int i = 0; i < 4; ++i) {
        int s = i * 256 + tid;
        int c = s >> 2, tq = s & 3;
        gl2lds16(feats4 + (((long long)(b * C + c0 + c)) << 7) + (t0 >> 2) + tq,
                 fl4 + s);
    }
    __syncthreads();

    int dg = tid & 31;
    int tg = tid >> 5;
    float4 a0 = make_float4(0.f, 0.f, 0.f, 0.f);
    float4 a1 = make_float4(0.f, 0.f, 0.f, 0.f);
    const float4* WpT4 = reinterpret_cast<const float4*>(WpT);
#pragma unroll 8
    for (int c = 0; c < 256; ++c) {
        float2 m2 = *reinterpret_cast<const float2*>(&fl[c * 16 + tg * 2]);
        float4 wv = WpT4[(long long)(c0 + c) * 32 + dg];
        a0.x += m2.x * wv.x; a0.y += m2.x * wv.y; a0.z += m2.x * wv.z; a0.w += m2.x * wv.w;
        a1.x += m2.y * wv.x; a1.y += m2.y * wv.y; a1.z += m2.y * wv.z; a1.w += m2.y * wv.w;
    }

    float4* part4 = reinterpret_cast<float4*>(part);
    long long row = (long long)kc * (BATCH * T) + b * T + t0 + tg * 2;
    part4[row * 32 + dg] = a0;
    part4[(row + 1) * 32 + dg] = a1;
}

// ---------------------------------------------------------------------------
// norm: reduce 8 split-K partials + L2 normalize -> xn[b*T+t][d]
// ---------------------------------------------------------------------------
__global__ __launch_bounds__(128) void norm_kernel(const float* __restrict__ part,
                                                   float* __restrict__ xn) {
    int bt = blockIdx.x;
    int tid = threadIdx.x;
    float v = 0.f;
#pragma unroll
    for (int kc = 0; kc < 8; ++kc)
        v += part[((long long)kc * (BATCH * T) + bt) * D + tid];
    float sq = v * v;
#pragma unroll
    for (int off = 1; off < 64; off <<= 1) sq += __shfl_xor(sq, off);
    __shared__ float red[2];
    if ((tid & 63) == 0) red[tid >> 6] = sq;
    __syncthreads();
    float n2 = red[0] + red[1];
    float scale = 1.0f / fmaxf(sqrtf(n2), 1e-12f);
    xn[(long long)bt * D + tid] = v * scale;
}

// ---------------------------------------------------------------------------
// simfc: banded sims + FC + bias + relu (verified rounds 1-3)
// ---------------------------------------------------------------------------
__global__ __launch_bounds__(128) void simfc_kernel(const float* __restrict__ xn,
                                                    const float* __restrict__ WfT,
                                                    const float* __restrict__ bf,
                                                    float* __restrict__ out) {
    int bt = blockIdx.x;
    int b = bt >> 9, t = bt & 511;
    int tid = threadIdx.x;
    __shared__ __align__(16) float q[D];
    __shared__ float sim[L];
    q[tid] = xn[(long long)bt * D + tid];
    __syncthreads();

    if (tid < L) {
        float acc = 0.f;
        int s = t + tid - HALF;
        if (s >= 0 && s < T) {
            const float4* xr = reinterpret_cast<const float4*>(xn + (((long long)b << 9) + s) * D);
            const float4* q4 = reinterpret_cast<const float4*>(q);
#pragma unroll
            for (int d4 = 0; d4 < D / 4; ++d4) {
                float4 xv = xr[d4];
                float4 qv = q4[d4];
                acc += qv.x * xv.x + qv.y * xv.y + qv.z * xv.z + qv.w * xv.w;
            }
        }
        sim[tid] = acc;
    }
    __syncthreads();

    float acc = bf[tid];
#pragma unroll 4
    for (int l = 0; l < L; ++l) acc += sim[l] * WfT[l * OUTD + tid];
    out[(long long)bt * OUTD + tid] = fmaxf(acc, 0.0f);
}

// ---------------------------------------------------------------------------
extern "C" void kernel_launch(void* const* d_in, const int* in_sizes, int n_in,
                              void* d_out, int out_size, void* d_ws, size_t ws_size,
                              hipStream_t stream) {
    const float* x1 = (const float*)d_in[0];
    const float* x2 = (const float*)d_in[1];
    const float* Wp = (const float*)d_in[2];
    const float* Wf = (const float*)d_in[3];
    const float* bf = (const float*)d_in[4];
    float* out = (float*)d_out;

    float* ws = (float*)d_ws;
    float* WpT   = ws;                   // 2048*128    = 262144 floats
    float* WfT   = WpT + 262144;         // 101*128     = 12928
    float* part  = WfT + 12928;          // 8*2048*128  = 2097152
    float* xn    = part + 2097152;       // 4*512*128   = 262144
    float* feats = xn + 262144;          // 4*2048*512  = 4194304

    hipLaunchKernelGGL(prep_kernel, dim3(307),  dim3(256), 0, stream, Wp, Wf, WpT, WfT);
    hipLaunchKernelGGL(mean_kernel, dim3(8192), dim3(256), 0, stream, x1, x2, feats);
    hipLaunchKernelGGL(proj_kernel, dim3(1024), dim3(256), 0, stream, feats, WpT, part);
    hipLaunchKernelGGL(norm_kernel, dim3(2048), dim3(128), 0, stream, part, xn);
    hipLaunchKernelGGL(simfc_kernel, dim3(2048), dim3(128), 0, stream, xn, WfT, bf, out);
}

// Round 6
// 208.351 us; speedup vs baseline: 1.0959x; 1.0959x over previous
//
#include <hip/hip_runtime.h>

#define BATCH 4
#define CIN 1024
#define T 512
#define HW 49
#define C 2048
#define D 128
#define L 101
#define HALF 50
#define OUTD 128

#if defined(__has_builtin)
#if __has_builtin(__builtin_amdgcn_global_load_lds)
#define HAS_GLLDS 1
#endif
#endif

__device__ __forceinline__ void gl2lds16(const float4* g, float4* l) {
#ifdef HAS_GLLDS
    __builtin_amdgcn_global_load_lds(
        (const __attribute__((address_space(1))) void*)g,
        (__attribute__((address_space(3))) void*)l, 16, 0, 0);
#else
    *l = *g;   // host-pass placeholder; device always takes HAS_GLLDS
#endif
}

// NT (non-temporal / streaming) variant: aux bit1 = nt on gfx94x+.
__device__ __forceinline__ void gl2lds16_nt(const float4* g, float4* l) {
#ifdef HAS_GLLDS
    __builtin_amdgcn_global_load_lds(
        (const __attribute__((address_space(1))) void*)g,
        (__attribute__((address_space(3))) void*)l, 16, 0, 2);
#else
    *l = *g;   // host-pass placeholder; device always takes HAS_GLLDS
#endif
}

// ---------------------------------------------------------------------------
// prep: tiled transpose Wp [D][C] -> WpT [C][D]; Wf [OUTD][L] -> WfT [L][OUTD]
// ---------------------------------------------------------------------------
__global__ __launch_bounds__(256) void prep_kernel(const float* __restrict__ Wp,
                                                   const float* __restrict__ Wf,
                                                   float* __restrict__ WpT,
                                                   float* __restrict__ WfT) {
    __shared__ float tile[32][33];
    int bid = blockIdx.x;
    int tid = threadIdx.x;
    if (bid < 256) {
        int ct = bid & 63, dt = bid >> 6;
        int c0 = ct * 32, d0 = dt * 32;
        int col = tid & 31, row = tid >> 5;
#pragma unroll
        for (int i = 0; i < 4; ++i) {
            int dl = row + i * 8;
            tile[dl][col] = Wp[(long long)(d0 + dl) * C + c0 + col];
        }
        __syncthreads();
#pragma unroll
        for (int i = 0; i < 4; ++i) {
            int cc = row + i * 8;
            WpT[(long long)(c0 + cc) * D + d0 + col] = tile[col][cc];
        }
    } else {
        int idx = (bid - 256) * 256 + tid;
        if (idx < L * OUTD) {
            int l = idx >> 7, o = idx & 127;
            WfT[idx] = Wf[o * L + l];
        }
    }
}

// ---------------------------------------------------------------------------
// mean: spatial mean over 49 -> feats[b][c][t].
// Round-4 structure (8192 blocks x 4 chunks of 128 rows, double-buffered
// global_load_lds, counted vmcnt, raw s_barrier), ONE change: staging loads
// carry the NT cache policy (aux=2) — streaming reads never re-read should
// not thrash L2/L3 insertion.
// ---------------------------------------------------------------------------
__global__ __launch_bounds__(256) void mean_kernel(const float* __restrict__ x1,
                                                   const float* __restrict__ x2,
                                                   float* __restrict__ feats) {
    __shared__ __align__(16) float4 buf[2][1568];        // 2 x 25088 B

    const long long Mrows = (long long)BATCH * CIN * T;  // 2097152 per input
    long long row0 = (long long)blockIdx.x * 512;        // 4 chunks x 128 rows
    const float* src;
    long long m0;
    int half;
    if (row0 < Mrows) { src = x1; m0 = row0; half = 0; }
    else              { src = x2; m0 = row0 - Mrows; half = 1; }

    const float4* src4 = reinterpret_cast<const float4*>(src) + (((long long)m0 * HW) >> 2);
    int tid  = threadIdx.x;
    int w    = tid >> 6;      // wave id 0..3
    int lane = tid & 63;

    // per-chunk float4 span = 128*49/4 = 1568; per wave 392 = 6*64 + 8
    const int wofs = w * 392;

    // reduce-phase ids
    int r = tid >> 1, p = tid & 1;

    auto issue = [&](int ck) {
        const float4* gb = src4 + (long long)ck * 1568 + wofs;
        float4* lb = &buf[ck & 1][wofs];
#pragma unroll
        for (int k = 0; k < 6; ++k)
            gl2lds16_nt(gb + k * 64 + lane, lb + k * 64 + lane);
        if (lane < 8)
            gl2lds16_nt(gb + 384 + lane, lb + 384 + lane);
    };

    issue(0);   // prologue

#pragma unroll
    for (int ck = 0; ck < 4; ++ck) {
        if (ck < 3) {
            issue(ck + 1);
            asm volatile("s_waitcnt vmcnt(7)" ::: "memory");
        } else {
            asm volatile("s_waitcnt vmcnt(0)" ::: "memory");
        }
        __builtin_amdgcn_s_barrier();          // chunk ck data ready (all waves)
        __builtin_amdgcn_sched_barrier(0);     // pin: no LDS reads above

        // reduce: 2 threads per row, 128 rows
        const float* rowp = reinterpret_cast<const float*>(buf[ck & 1]) + r * HW + p * 24;
        float s0 = 0.f, s1 = 0.f, s2 = 0.f, s3 = 0.f;
#pragma unroll
        for (int j = 0; j < 6; ++j) {
            s0 += rowp[j];
            s1 += rowp[6 + j];
            s2 += rowp[12 + j];
            s3 += rowp[18 + j];
        }
        float s = (s0 + s1) + (s2 + s3);
        if (p == 0) s += reinterpret_cast<const float*>(buf[ck & 1])[r * HW + 48];
        s += __shfl_xor(s, 1);
        if (p == 0) {
            long long m = m0 + ck * 128 + r;
            long long b = m >> 19;                 // / (1024*512)
            long long rem = m & ((1LL << 19) - 1); // c*512 + t
            feats[(b << 20) + ((long long)half << 19) + rem] = s * (1.0f / 49.0f);
        }
        __builtin_amdgcn_s_barrier();          // safe to overwrite buf[ck&1]
    }
}

// ---------------------------------------------------------------------------
// proj: x[b,t,d] = sum_c feats[b,c,t] * WpT[c,d], split-K.
// grid = 4(b) * 32(t-tile of 16) * 8(kc of 256 c) = 1024 blocks, 256 thr.
// ---------------------------------------------------------------------------
__global__ __launch_bounds__(256) void proj_kernel(const float* __restrict__ feats,
                                                   const float* __restrict__ WpT,
                                                   float* __restrict__ part) {
    int bid = blockIdx.x;
    int kc = bid & 7;
    int tt = (bid >> 3) & 31;
    int b  = bid >> 8;
    int c0 = kc * 256;
    int t0 = tt * 16;

    __shared__ __align__(16) float fl[256 * 16];   // 16 KB
    float4* fl4 = reinterpret_cast<float4*>(fl);
    const float4* feats4 = reinterpret_cast<const float4*>(feats);
    int tid = threadIdx.x;
#pragma unroll
    for (int i = 0; i < 4; ++i) {
        int s = i * 256 + tid;
        int c = s >> 2, tq = s & 3;
        gl2lds16(feats4 + (((long long)(b * C + c0 + c)) << 7) + (t0 >> 2) + tq,
                 fl4 + s);
    }
    __syncthreads();

    int dg = tid & 31;
    int tg = tid >> 5;
    float4 a0 = make_float4(0.f, 0.f, 0.f, 0.f);
    float4 a1 = make_float4(0.f, 0.f, 0.f, 0.f);
    const float4* WpT4 = reinterpret_cast<const float4*>(WpT);
#pragma unroll 8
    for (int c = 0; c < 256; ++c) {
        float2 m2 = *reinterpret_cast<const float2*>(&fl[c * 16 + tg * 2]);
        float4 wv = WpT4[(long long)(c0 + c) * 32 + dg];
        a0.x += m2.x * wv.x; a0.y += m2.x * wv.y; a0.z += m2.x * wv.z; a0.w += m2.x * wv.w;
        a1.x += m2.y * wv.x; a1.y += m2.y * wv.y; a1.z += m2.y * wv.z; a1.w += m2.y * wv.w;
    }

    float4* part4 = reinterpret_cast<float4*>(part);
    long long row = (long long)kc * (BATCH * T) + b * T + t0 + tg * 2;
    part4[row * 32 + dg] = a0;
    part4[(row + 1) * 32 + dg] = a1;
}

// ---------------------------------------------------------------------------
// norm: reduce 8 split-K partials + L2 normalize -> xn[b*T+t][d]
// ---------------------------------------------------------------------------
__global__ __launch_bounds__(128) void norm_kernel(const float* __restrict__ part,
                                                   float* __restrict__ xn) {
    int bt = blockIdx.x;
    int tid = threadIdx.x;
    float v = 0.f;
#pragma unroll
    for (int kc = 0; kc < 8; ++kc)
        v += part[((long long)kc * (BATCH * T) + bt) * D + tid];
    float sq = v * v;
#pragma unroll
    for (int off = 1; off < 64; off <<= 1) sq += __shfl_xor(sq, off);
    __shared__ float red[2];
    if ((tid & 63) == 0) red[tid >> 6] = sq;
    __syncthreads();
    float n2 = red[0] + red[1];
    float scale = 1.0f / fmaxf(sqrtf(n2), 1e-12f);
    xn[(long long)bt * D + tid] = v * scale;
}

// ---------------------------------------------------------------------------
// simfc: banded sims + FC + bias + relu (verified rounds 1-4)
// ---------------------------------------------------------------------------
__global__ __launch_bounds__(128) void simfc_kernel(const float* __restrict__ xn,
                                                    const float* __restrict__ WfT,
                                                    const float* __restrict__ bf,
                                                    float* __restrict__ out) {
    int bt = blockIdx.x;
    int b = bt >> 9, t = bt & 511;
    int tid = threadIdx.x;
    __shared__ __align__(16) float q[D];
    __shared__ float sim[L];
    q[tid] = xn[(long long)bt * D + tid];
    __syncthreads();

    if (tid < L) {
        float acc = 0.f;
        int s = t + tid - HALF;
        if (s >= 0 && s < T) {
            const float4* xr = reinterpret_cast<const float4*>(xn + (((long long)b << 9) + s) * D);
            const float4* q4 = reinterpret_cast<const float4*>(q);
#pragma unroll
            for (int d4 = 0; d4 < D / 4; ++d4) {
                float4 xv = xr[d4];
                float4 qv = q4[d4];
                acc += qv.x * xv.x + qv.y * xv.y + qv.z * xv.z + qv.w * xv.w;
            }
        }
        sim[tid] = acc;
    }
    __syncthreads();

    float acc = bf[tid];
#pragma unroll 4
    for (int l = 0; l < L; ++l) acc += sim[l] * WfT[l * OUTD + tid];
    out[(long long)bt * OUTD + tid] = fmaxf(acc, 0.0f);
}

// ---------------------------------------------------------------------------
extern "C" void kernel_launch(void* const* d_in, const int* in_sizes, int n_in,
                              void* d_out, int out_size, void* d_ws, size_t ws_size,
                              hipStream_t stream) {
    const float* x1 = (const float*)d_in[0];
    const float* x2 = (const float*)d_in[1];
    const float* Wp = (const float*)d_in[2];
    const float* Wf = (const float*)d_in[3];
    const float* bf = (const float*)d_in[4];
    float* out = (float*)d_out;

    float* ws = (float*)d_ws;
    float* WpT   = ws;                   // 2048*128    = 262144 floats
    float* WfT   = WpT + 262144;         // 101*128     = 12928
    float* part  = WfT + 12928;          // 8*2048*128  = 2097152
    float* xn    = part + 2097152;       // 4*512*128   = 262144
    float* feats = xn + 262144;          // 4*2048*512  = 4194304

    hipLaunchKernelGGL(prep_kernel, dim3(307),  dim3(256), 0, stream, Wp, Wf, WpT, WfT);
    hipLaunchKernelGGL(mean_kernel, dim3(8192), dim3(256), 0, stream, x1, x2, feats);
    hipLaunchKernelGGL(proj_kernel, dim3(1024), dim3(256), 0, stream, feats, WpT, part);
    hipLaunchKernelGGL(norm_kernel, dim3(2048), dim3(128), 0, stream, part, xn);
    hipLaunchKernelGGL(simfc_kernel, dim3(2048), dim3(128), 0, stream, xn, WfT, bf, out);
}